// Round 1
// baseline (334.392 us; speedup 1.0000x reference)
//
#include <hip/hip_runtime.h>
#include <hip/hip_bf16.h>

#define B_ 4
#define S_ 1024
#define D_ 2048
#define H_ 16
#define G_ 4
#define HD_ 128
#define NQKV_ 3072
#define SCALE_ 0.08838834764831845f
#define EPS_ 1e-6f

typedef __attribute__((ext_vector_type(8))) short bf16x8;
typedef __attribute__((ext_vector_type(4))) float f32x4;

__device__ __forceinline__ float bf2f(unsigned short u){
  union { unsigned int i; float f; } v; v.i = ((unsigned int)u) << 16; return v.f;
}
__device__ __forceinline__ unsigned short f2bf(float f){
  union { float f; unsigned int i; } v; v.f = f;
  unsigned int x = v.i;
  return (unsigned short)((x + 0x7fffu + ((x >> 16) & 1u)) >> 16);
}

// ---------------- x -> bf16 ----------------
__global__ void cvt_bf16(const float* __restrict__ src, unsigned short* __restrict__ dst){
  int i = blockIdx.x * 256 + threadIdx.x;
  const float4 v = ((const float4*)src)[i];
  ushort4 o;
  o.x = f2bf(v.x); o.y = f2bf(v.y); o.z = f2bf(v.z); o.w = f2bf(v.w);
  ((ushort4*)dst)[i] = o;
}

// ---------------- W (KxN f32) -> Wt (NxK bf16), dst row stride 2048 ----------------
__global__ void transpose_cvt(const float* __restrict__ src, unsigned short* __restrict__ dst,
                              int N, int rowoff){
  __shared__ float tile[64][65];
  const int n0 = blockIdx.x * 64, k0 = blockIdx.y * 64;
  const int c = threadIdx.x & 63, rb = threadIdx.x >> 6;
  #pragma unroll
  for (int j = 0; j < 16; j++){
    int r = rb + j * 4;
    tile[r][c] = src[(size_t)(k0 + r) * N + n0 + c];
  }
  __syncthreads();
  #pragma unroll
  for (int j = 0; j < 16; j++){
    int r = rb + j * 4;
    dst[(size_t)(n0 + r + rowoff) * 2048 + k0 + c] = f2bf(tile[c][r]);
  }
}

// ---------------- GEMM: C[M][N] = A[M][K] @ Bt[N][K]^T + bias ----------------
// MODE 1: write bf16, qkv bias select (bq|bk|bv). MODE 0: write f32, bias b0.
template<int MODE>
__global__ __launch_bounds__(256, 2) void gemm_bt(const unsigned short* __restrict__ A,
    const unsigned short* __restrict__ Bt,
    const float* __restrict__ b0, const float* __restrict__ b1, const float* __restrict__ b2,
    void* __restrict__ Cout, int M, int N, int K){
  const int tid = threadIdx.x, wid = tid >> 6, lane = tid & 63;
  const int l15 = lane & 15, l4 = lane >> 4;
  const int bm = blockIdx.y * 128, bn = blockIdx.x * 128;
  const int wr = wid >> 1, wc = wid & 1;
  __shared__ __align__(16) unsigned short As[128][56];
  __shared__ __align__(16) unsigned short Bs[128][56];
  f32x4 acc[4][4];
  #pragma unroll
  for (int m2 = 0; m2 < 4; m2++)
    #pragma unroll
    for (int n2 = 0; n2 < 4; n2++) acc[m2][n2] = (f32x4){0.f, 0.f, 0.f, 0.f};

  for (int k0 = 0; k0 < K; k0 += 32){
    __syncthreads();
    #pragma unroll
    for (int i = 0; i < 2; i++){
      int c = tid + i * 256;
      int row = c >> 2, off = (c & 3) * 8;
      *(bf16x8*)&As[row][off] = *(const bf16x8*)&A[(size_t)(bm + row) * K + k0 + off];
      *(bf16x8*)&Bs[row][off] = *(const bf16x8*)&Bt[(size_t)(bn + row) * K + k0 + off];
    }
    __syncthreads();
    bf16x8 af[4], bfr[4];
    #pragma unroll
    for (int m2 = 0; m2 < 4; m2++) af[m2] = *(const bf16x8*)&As[wr * 64 + m2 * 16 + l15][l4 * 8];
    #pragma unroll
    for (int n2 = 0; n2 < 4; n2++) bfr[n2] = *(const bf16x8*)&Bs[wc * 64 + n2 * 16 + l15][l4 * 8];
    #pragma unroll
    for (int m2 = 0; m2 < 4; m2++)
      #pragma unroll
      for (int n2 = 0; n2 < 4; n2++)
        acc[m2][n2] = __builtin_amdgcn_mfma_f32_16x16x32_bf16(af[m2], bfr[n2], acc[m2][n2], 0, 0, 0);
  }
  #pragma unroll
  for (int m2 = 0; m2 < 4; m2++)
    #pragma unroll
    for (int n2 = 0; n2 < 4; n2++){
      int col = bn + wc * 64 + n2 * 16 + l15;
      float bias;
      if (MODE == 1) bias = col < 2048 ? b0[col] : (col < 2560 ? b1[col - 2048] : b2[col - 2560]);
      else           bias = b0[col];
      #pragma unroll
      for (int r = 0; r < 4; r++){
        int row = bm + wr * 64 + m2 * 16 + l4 * 4 + r;
        float v = acc[m2][n2][r] + bias;
        if (MODE == 1) ((unsigned short*)Cout)[(size_t)row * N + col] = f2bf(v);
        else           ((float*)Cout)[(size_t)row * N + col] = v;
      }
    }
}

// ---------------- fused RMSNorm + RoPE, in place on q/k parts of qkv ----------------
__global__ void rmsrope(unsigned short* __restrict__ qkv, const float* __restrict__ qn,
                        const float* __restrict__ kn){
  const int w = blockIdx.x * 4 + (threadIdx.x >> 6);
  const int lane = threadIdx.x & 63;
  const int t = w / 20, sub = w % 20;
  const int s = t & (S_ - 1);
  const bool isq = sub < 16;
  unsigned short* row;
  const float* sc;
  if (isq){ row = qkv + (size_t)t * NQKV_ + sub * HD_; sc = qn; }
  else    { row = qkv + (size_t)t * NQKV_ + 2048 + (sub - 16) * HD_; sc = kn; }
  unsigned int pr = *(const unsigned int*)&row[2 * lane];
  float xe = bf2f((unsigned short)(pr & 0xffffu));
  float xo = bf2f((unsigned short)(pr >> 16));
  float ss = xe * xe + xo * xo;
  #pragma unroll
  for (int o = 1; o < 64; o <<= 1) ss += __shfl_xor(ss, o);
  float rn = rsqrtf(ss * (1.0f / 128.0f) + EPS_);
  xe = xe * rn * sc[2 * lane];
  xo = xo * rn * sc[2 * lane + 1];
  float inv = powf(10000.0f, -(float)lane * (1.0f / 64.0f));
  float th = (float)s * inv;
  float sn = sinf(th), cs = cosf(th);
  float oe = xe * cs - xo * sn;
  float oo = xe * sn + xo * cs;
  if (isq){ oe *= SCALE_; oo *= SCALE_; }
  *(unsigned int*)&row[2 * lane] = (unsigned int)f2bf(oe) | ((unsigned int)f2bf(oo) << 16);
}

// ---------------- V -> V^T per (b,g): vt[(bg*128+d)*1024 + s] ----------------
__global__ void vtrans(const unsigned short* __restrict__ qkv, unsigned short* __restrict__ vt){
  __shared__ unsigned short tile[64][65];
  const int s0 = blockIdx.x * 64, d0 = blockIdx.y * 64;
  const int bg = blockIdx.z, b = bg >> 2, g = bg & 3;
  const int c = threadIdx.x & 63, rb = threadIdx.x >> 6;
  #pragma unroll
  for (int j = 0; j < 16; j++){
    int r = rb + j * 4;
    tile[r][c] = qkv[((size_t)b * S_ + s0 + r) * NQKV_ + 2560 + g * HD_ + d0 + c];
  }
  __syncthreads();
  #pragma unroll
  for (int j = 0; j < 16; j++){
    int r = rb + j * 4;
    vt[((size_t)bg * HD_ + d0 + r) * (size_t)S_ + s0 + c] = tile[c][r];
  }
}

// ---------------- flash attention, MFMA, causal GQA ----------------
__global__ __launch_bounds__(256, 2) void attn(const unsigned short* __restrict__ qkv,
    const unsigned short* __restrict__ vt, unsigned short* __restrict__ outb){
  const int qt = blockIdx.x, h = blockIdx.y, b = blockIdx.z;
  const int g = h >> 2;
  const int tid = threadIdx.x, w = tid >> 6, lane = tid & 63;
  const int l15 = lane & 15, l4 = lane >> 4;
  __shared__ __align__(16) unsigned short Ks[64][136];
  __shared__ __align__(16) unsigned short Vt[128][72];
  __shared__ __align__(16) unsigned short Pl[4][16][72];

  bf16x8 qf[4];
  {
    const size_t qbase = ((size_t)b * S_ + qt * 64 + w * 16 + l15) * NQKV_ + h * HD_;
    #pragma unroll
    for (int c = 0; c < 4; c++) qf[c] = *(const bf16x8*)&qkv[qbase + c * 32 + l4 * 8];
  }
  f32x4 o[8];
  #pragma unroll
  for (int i = 0; i < 8; i++) o[i] = (f32x4){0.f, 0.f, 0.f, 0.f};
  float m_[4], l_[4];
  #pragma unroll
  for (int r = 0; r < 4; r++){ m_[r] = -1e30f; l_[r] = 0.f; }

  for (int kt = 0; kt <= qt; ++kt){
    __syncthreads();
    #pragma unroll
    for (int i = 0; i < 4; i++){
      int cc = tid + i * 256; int row = cc >> 4, off = (cc & 15) * 8;
      *(bf16x8*)&Ks[row][off] =
        *(const bf16x8*)&qkv[((size_t)b * S_ + kt * 64 + row) * NQKV_ + 2048 + g * HD_ + off];
    }
    #pragma unroll
    for (int i = 0; i < 4; i++){
      int cc = tid + i * 256; int row = cc >> 3, off = (cc & 7) * 8;
      *(bf16x8*)&Vt[row][off] =
        *(const bf16x8*)&vt[((size_t)(b * G_ + g) * HD_ + row) * (size_t)S_ + kt * 64 + off];
    }
    __syncthreads();

    f32x4 sa[4];
    #pragma unroll
    for (int kb = 0; kb < 4; kb++){
      f32x4 acc = (f32x4){0.f, 0.f, 0.f, 0.f};
      #pragma unroll
      for (int c = 0; c < 4; c++){
        bf16x8 kf = *(const bf16x8*)&Ks[kb * 16 + l15][c * 32 + l4 * 8];
        acc = __builtin_amdgcn_mfma_f32_16x16x32_bf16(qf[c], kf, acc, 0, 0, 0);
      }
      sa[kb] = acc;
    }
    #pragma unroll
    for (int kb = 0; kb < 4; kb++){
      #pragma unroll
      for (int r = 0; r < 4; r++){
        float v = sa[kb][r] * SCALE_;
        int key = kt * 64 + kb * 16 + l15;
        int qrow = qt * 64 + w * 16 + l4 * 4 + r;
        sa[kb][r] = (key > qrow) ? -1e30f : v;
      }
    }
    float al[4], rs[4];
    #pragma unroll
    for (int r = 0; r < 4; r++){
      float tm = fmaxf(fmaxf(sa[0][r], sa[1][r]), fmaxf(sa[2][r], sa[3][r]));
      tm = fmaxf(tm, __shfl_xor(tm, 1));
      tm = fmaxf(tm, __shfl_xor(tm, 2));
      tm = fmaxf(tm, __shfl_xor(tm, 4));
      tm = fmaxf(tm, __shfl_xor(tm, 8));
      float mn = fmaxf(m_[r], tm);
      al[r] = __expf(m_[r] - mn);
      m_[r] = mn;
      rs[r] = 0.f;
    }
    #pragma unroll
    for (int kb = 0; kb < 4; kb++){
      #pragma unroll
      for (int r = 0; r < 4; r++){
        float p = __expf(sa[kb][r] - m_[r]);
        sa[kb][r] = p;
        rs[r] += p;
      }
    }
    #pragma unroll
    for (int r = 0; r < 4; r++){
      rs[r] += __shfl_xor(rs[r], 1);
      rs[r] += __shfl_xor(rs[r], 2);
      rs[r] += __shfl_xor(rs[r], 4);
      rs[r] += __shfl_xor(rs[r], 8);
      l_[r] = l_[r] * al[r] + rs[r];
    }
    #pragma unroll
    for (int db = 0; db < 8; db++){
      #pragma unroll
      for (int r = 0; r < 4; r++) o[db][r] *= al[r];
    }
    #pragma unroll
    for (int kb = 0; kb < 4; kb++){
      #pragma unroll
      for (int r = 0; r < 4; r++)
        Pl[w][l4 * 4 + r][kb * 16 + l15] = f2bf(sa[kb][r]);
    }
    bf16x8 pf0 = *(const bf16x8*)&Pl[w][l15][l4 * 8];
    bf16x8 pf1 = *(const bf16x8*)&Pl[w][l15][32 + l4 * 8];
    #pragma unroll
    for (int db = 0; db < 8; db++){
      f32x4 acc = o[db];
      bf16x8 vf0 = *(const bf16x8*)&Vt[db * 16 + l15][l4 * 8];
      acc = __builtin_amdgcn_mfma_f32_16x16x32_bf16(pf0, vf0, acc, 0, 0, 0);
      bf16x8 vf1 = *(const bf16x8*)&Vt[db * 16 + l15][32 + l4 * 8];
      acc = __builtin_amdgcn_mfma_f32_16x16x32_bf16(pf1, vf1, acc, 0, 0, 0);
      o[db] = acc;
    }
  }
  float li[4];
  #pragma unroll
  for (int r = 0; r < 4; r++) li[r] = 1.0f / l_[r];
  #pragma unroll
  for (int db = 0; db < 8; db++){
    #pragma unroll
    for (int r = 0; r < 4; r++){
      size_t idx = ((size_t)b * S_ + qt * 64 + w * 16 + l4 * 4 + r) * (size_t)D_ + h * HD_ + db * 16 + l15;
      outb[idx] = f2bf(o[db][r] * li[r]);
    }
  }
}

extern "C" void kernel_launch(void* const* d_in, const int* in_sizes, int n_in,
                              void* d_out, int out_size, void* d_ws, size_t ws_size,
                              hipStream_t stream){
  const float* x  = (const float*)d_in[0];
  const float* Wq = (const float*)d_in[1];
  const float* bq = (const float*)d_in[2];
  const float* Wk = (const float*)d_in[3];
  const float* bk = (const float*)d_in[4];
  const float* Wv = (const float*)d_in[5];
  const float* bv = (const float*)d_in[6];
  const float* Wo = (const float*)d_in[7];
  const float* bo = (const float*)d_in[8];
  const float* qn = (const float*)d_in[9];
  const float* kn = (const float*)d_in[10];
  float* out = (float*)d_out;

  char* ws = (char*)d_ws;
  unsigned short* xb    = (unsigned short*)(ws + 0);          // 16,777,216 B
  unsigned short* wqkvT = (unsigned short*)(ws + 16777216);   // 12,582,912 B
  unsigned short* woT   = (unsigned short*)(ws + 29360128);   //  8,388,608 B
  unsigned short* qkv   = (unsigned short*)(ws + 37748736);   // 25,165,824 B
  unsigned short* attnO = (unsigned short*)(ws + 62914560);   // 16,777,216 B
  unsigned short* vt    = (unsigned short*)(ws + 79691776);   //  4,194,304 B

  cvt_bf16<<<8192, 256, 0, stream>>>(x, xb);
  transpose_cvt<<<dim3(32, 32), 256, 0, stream>>>(Wq, wqkvT, 2048, 0);
  transpose_cvt<<<dim3(8, 32),  256, 0, stream>>>(Wk, wqkvT, 512, 2048);
  transpose_cvt<<<dim3(8, 32),  256, 0, stream>>>(Wv, wqkvT, 512, 2560);
  transpose_cvt<<<dim3(32, 32), 256, 0, stream>>>(Wo, woT, 2048, 0);
  gemm_bt<1><<<dim3(24, 32), 256, 0, stream>>>(xb, wqkvT, bq, bk, bv, (void*)qkv, 4096, 3072, 2048);
  rmsrope<<<20480, 256, 0, stream>>>(qkv, qn, kn);
  vtrans<<<dim3(16, 2, 16), 256, 0, stream>>>(qkv, vt);
  attn<<<dim3(16, 16, 4), 256, 0, stream>>>(qkv, vt, attnO);
  gemm_bt<0><<<dim3(16, 32), 256, 0, stream>>>(attnO, woT, bo, nullptr, nullptr, (void*)out, 4096, 2048, 2048);
}

// Round 2
// 285.331 us; speedup vs baseline: 1.1719x; 1.1719x over previous
//
#include <hip/hip_runtime.h>
#include <hip/hip_bf16.h>

#define B_ 4
#define S_ 1024
#define D_ 2048
#define H_ 16
#define G_ 4
#define HD_ 128
#define NQKV_ 3072
#define SCALE_ 0.08838834764831845f
#define EPS_ 1e-6f

typedef __attribute__((ext_vector_type(8))) short bf16x8;
typedef __attribute__((ext_vector_type(4))) float f32x4;

__device__ __forceinline__ float bf2f(unsigned short u){
  union { unsigned int i; float f; } v; v.i = ((unsigned int)u) << 16; return v.f;
}
__device__ __forceinline__ unsigned short f2bf(float f){
  union { float f; unsigned int i; } v; v.f = f;
  unsigned int x = v.i;
  return (unsigned short)((x + 0x7fffu + ((x >> 16) & 1u)) >> 16);
}
__device__ __forceinline__ void gld16(unsigned short* lds, const unsigned short* g){
  __builtin_amdgcn_global_load_lds(
      (const __attribute__((address_space(1))) unsigned int*)g,
      (__attribute__((address_space(3))) unsigned int*)lds, 16, 0, 0);
}

// ---------------- x -> bf16 ----------------
__global__ void cvt_bf16(const float* __restrict__ src, unsigned short* __restrict__ dst){
  int i = blockIdx.x * 256 + threadIdx.x;
  const float4 v = ((const float4*)src)[i];
  ushort4 o;
  o.x = f2bf(v.x); o.y = f2bf(v.y); o.z = f2bf(v.z); o.w = f2bf(v.w);
  ((ushort4*)dst)[i] = o;
}

// ---------------- W (KxN f32) -> Wt (NxK bf16), dst row stride 2048 ----------------
__global__ void transpose_cvt(const float* __restrict__ src, unsigned short* __restrict__ dst,
                              int N, int rowoff){
  __shared__ float tile[64][65];
  const int n0 = blockIdx.x * 64, k0 = blockIdx.y * 64;
  const int c = threadIdx.x & 63, rb = threadIdx.x >> 6;
  #pragma unroll
  for (int j = 0; j < 16; j++){
    int r = rb + j * 4;
    tile[r][c] = src[(size_t)(k0 + r) * N + n0 + c];
  }
  __syncthreads();
  #pragma unroll
  for (int j = 0; j < 16; j++){
    int r = rb + j * 4;
    dst[(size_t)(n0 + r + rowoff) * 2048 + k0 + c] = f2bf(tile[c][r]);
  }
}

// ---------------- GEMM: C[M][N] = A[M][K] @ Bt[N][K]^T + bias ----------------
// global_load_lds staging (m97 structure): linear LDS [128][32], BK=32.
// MODE 1: write bf16, qkv bias select (bq|bk|bv). MODE 0: write f32, bias b0.
template<int MODE>
__global__ __launch_bounds__(256, 2) void gemm_bt(const unsigned short* __restrict__ A,
    const unsigned short* __restrict__ Bt,
    const float* __restrict__ b0, const float* __restrict__ b1, const float* __restrict__ b2,
    void* __restrict__ Cout, int M, int N, int K){
  const int tid = threadIdx.x, wid = tid >> 6, lane = tid & 63;
  const int l15 = lane & 15, l4 = lane >> 4;
  const int bm = blockIdx.y * 128, bn = blockIdx.x * 128;
  const int wr = wid >> 1, wc = wid & 1;
  __shared__ __align__(16) unsigned short As[128 * 32];
  __shared__ __align__(16) unsigned short Bs[128 * 32];

  // staging: 4 waves x 2 issues x (16 rows x 32 cols). lane l -> row l/4, elem col (l&3)*8.
  const int srow = wid * 32 + (lane >> 2);
  const int scol = (lane & 3) * 8;
  const unsigned short* pa0 = A  + (size_t)(bm + srow) * K + scol;
  const unsigned short* pa1 = pa0 + (size_t)16 * K;
  const unsigned short* pb0 = Bt + (size_t)(bn + srow) * K + scol;
  const unsigned short* pb1 = pb0 + (size_t)16 * K;
  unsigned short* la0 = As + wid * 1024;
  unsigned short* la1 = la0 + 512;
  unsigned short* lb0 = Bs + wid * 1024;
  unsigned short* lb1 = lb0 + 512;

  f32x4 acc[4][4];
  #pragma unroll
  for (int m2 = 0; m2 < 4; m2++)
    #pragma unroll
    for (int n2 = 0; n2 < 4; n2++) acc[m2][n2] = (f32x4){0.f, 0.f, 0.f, 0.f};

  for (int k0 = 0; k0 < K; k0 += 32){
    __syncthreads();
    gld16(la0, pa0 + k0);
    gld16(la1, pa1 + k0);
    gld16(lb0, pb0 + k0);
    gld16(lb1, pb1 + k0);
    __syncthreads();
    bf16x8 af[4], bfr[4];
    #pragma unroll
    for (int m2 = 0; m2 < 4; m2++) af[m2] = *(const bf16x8*)&As[(wr * 64 + m2 * 16 + l15) * 32 + l4 * 8];
    #pragma unroll
    for (int n2 = 0; n2 < 4; n2++) bfr[n2] = *(const bf16x8*)&Bs[(wc * 64 + n2 * 16 + l15) * 32 + l4 * 8];
    #pragma unroll
    for (int m2 = 0; m2 < 4; m2++)
      #pragma unroll
      for (int n2 = 0; n2 < 4; n2++)
        acc[m2][n2] = __builtin_amdgcn_mfma_f32_16x16x32_bf16(af[m2], bfr[n2], acc[m2][n2], 0, 0, 0);
  }
  #pragma unroll
  for (int m2 = 0; m2 < 4; m2++)
    #pragma unroll
    for (int n2 = 0; n2 < 4; n2++){
      int col = bn + wc * 64 + n2 * 16 + l15;
      float bias;
      if (MODE == 1) bias = col < 2048 ? b0[col] : (col < 2560 ? b1[col - 2048] : b2[col - 2560]);
      else           bias = b0[col];
      #pragma unroll
      for (int r = 0; r < 4; r++){
        int row = bm + wr * 64 + m2 * 16 + l4 * 4 + r;
        float v = acc[m2][n2][r] + bias;
        if (MODE == 1) ((unsigned short*)Cout)[(size_t)row * N + col] = f2bf(v);
        else           ((float*)Cout)[(size_t)row * N + col] = v;
      }
    }
}

// ---------------- fused RMSNorm + RoPE, in place on q/k parts of qkv ----------------
__global__ void rmsrope(unsigned short* __restrict__ qkv, const float* __restrict__ qn,
                        const float* __restrict__ kn){
  const int w = blockIdx.x * 4 + (threadIdx.x >> 6);
  const int lane = threadIdx.x & 63;
  const int t = w / 20, sub = w % 20;
  const int s = t & (S_ - 1);
  const bool isq = sub < 16;
  unsigned short* row;
  const float* sc;
  if (isq){ row = qkv + (size_t)t * NQKV_ + sub * HD_; sc = qn; }
  else    { row = qkv + (size_t)t * NQKV_ + 2048 + (sub - 16) * HD_; sc = kn; }
  unsigned int pr = *(const unsigned int*)&row[2 * lane];
  float xe = bf2f((unsigned short)(pr & 0xffffu));
  float xo = bf2f((unsigned short)(pr >> 16));
  float ss = xe * xe + xo * xo;
  #pragma unroll
  for (int o = 1; o < 64; o <<= 1) ss += __shfl_xor(ss, o);
  float rn = rsqrtf(ss * (1.0f / 128.0f) + EPS_);
  xe = xe * rn * sc[2 * lane];
  xo = xo * rn * sc[2 * lane + 1];
  float inv = powf(10000.0f, -(float)lane * (1.0f / 64.0f));
  float th = (float)s * inv;
  float sn = sinf(th), cs = cosf(th);
  float oe = xe * cs - xo * sn;
  float oo = xe * sn + xo * cs;
  if (isq){ oe *= SCALE_; oo *= SCALE_; }
  *(unsigned int*)&row[2 * lane] = (unsigned int)f2bf(oe) | ((unsigned int)f2bf(oo) << 16);
}

// ---------------- V -> V^T per (b,g): vt[(bg*128+d)*1024 + s] ----------------
__global__ void vtrans(const unsigned short* __restrict__ qkv, unsigned short* __restrict__ vt){
  __shared__ unsigned short tile[64][65];
  const int s0 = blockIdx.x * 64, d0 = blockIdx.y * 64;
  const int bg = blockIdx.z, b = bg >> 2, g = bg & 3;
  const int c = threadIdx.x & 63, rb = threadIdx.x >> 6;
  #pragma unroll
  for (int j = 0; j < 16; j++){
    int r = rb + j * 4;
    tile[r][c] = qkv[((size_t)b * S_ + s0 + r) * NQKV_ + 2560 + g * HD_ + d0 + c];
  }
  __syncthreads();
  #pragma unroll
  for (int j = 0; j < 16; j++){
    int r = rb + j * 4;
    vt[((size_t)bg * HD_ + d0 + r) * (size_t)S_ + s0 + c] = tile[c][r];
  }
}

// ---------------- flash attention, MFMA, causal GQA ----------------
// block = (32 q-rows, g, b); 4 waves = the 4 heads of group g sharing K/V staging.
__global__ __launch_bounds__(256, 2) void attn(const unsigned short* __restrict__ qkv,
    const unsigned short* __restrict__ vt, unsigned short* __restrict__ outb){
  const int qt = 31 - blockIdx.x;            // big (late-diagonal) blocks dispatch first
  const int g = blockIdx.y, b = blockIdx.z;
  const int tid = threadIdx.x, w = tid >> 6, lane = tid & 63;
  const int h = g * 4 + w;
  const int l15 = lane & 15, l4 = lane >> 4;
  const int nkt = qt / 2 + 1;                // 64-key tiles needed for rows [32qt,32qt+32)
  __shared__ __align__(16) unsigned short Ks[64][136];
  __shared__ __align__(16) unsigned short Vt[128][72];
  __shared__ __align__(16) unsigned short Pl[4][16][72];

  bf16x8 qf[2][4];
  #pragma unroll
  for (int m = 0; m < 2; m++){
    const size_t qbase = ((size_t)b * S_ + qt * 32 + m * 16 + l15) * NQKV_ + h * HD_;
    #pragma unroll
    for (int c = 0; c < 4; c++) qf[m][c] = *(const bf16x8*)&qkv[qbase + c * 32 + l4 * 8];
  }
  f32x4 o[2][8];
  #pragma unroll
  for (int m = 0; m < 2; m++)
    #pragma unroll
    for (int i = 0; i < 8; i++) o[m][i] = (f32x4){0.f, 0.f, 0.f, 0.f};
  float m_[2][4], l_[2][4];
  #pragma unroll
  for (int m = 0; m < 2; m++)
    #pragma unroll
    for (int r = 0; r < 4; r++){ m_[m][r] = -1e30f; l_[m][r] = 0.f; }

  for (int kt = 0; kt < nkt; ++kt){
    __syncthreads();
    #pragma unroll
    for (int i = 0; i < 4; i++){
      int cc = tid + i * 256; int row = cc >> 4, off = (cc & 15) * 8;
      *(bf16x8*)&Ks[row][off] =
        *(const bf16x8*)&qkv[((size_t)b * S_ + kt * 64 + row) * NQKV_ + 2048 + g * HD_ + off];
    }
    #pragma unroll
    for (int i = 0; i < 4; i++){
      int cc = tid + i * 256; int row = cc >> 3, off = (cc & 7) * 8;
      *(bf16x8*)&Vt[row][off] =
        *(const bf16x8*)&vt[((size_t)(b * G_ + g) * HD_ + row) * (size_t)S_ + kt * 64 + off];
    }
    __syncthreads();

    #pragma unroll
    for (int m = 0; m < 2; m++){
      f32x4 sa[4];
      #pragma unroll
      for (int kb = 0; kb < 4; kb++){
        f32x4 acc = (f32x4){0.f, 0.f, 0.f, 0.f};
        #pragma unroll
        for (int c = 0; c < 4; c++){
          bf16x8 kf = *(const bf16x8*)&Ks[kb * 16 + l15][c * 32 + l4 * 8];
          acc = __builtin_amdgcn_mfma_f32_16x16x32_bf16(qf[m][c], kf, acc, 0, 0, 0);
        }
        sa[kb] = acc;
      }
      #pragma unroll
      for (int kb = 0; kb < 4; kb++){
        #pragma unroll
        for (int r = 0; r < 4; r++){
          float v = sa[kb][r] * SCALE_;
          int key = kt * 64 + kb * 16 + l15;
          int qrow = qt * 32 + m * 16 + l4 * 4 + r;
          sa[kb][r] = (key > qrow) ? -1e30f : v;
        }
      }
      float al[4], rs[4];
      #pragma unroll
      for (int r = 0; r < 4; r++){
        float tm = fmaxf(fmaxf(sa[0][r], sa[1][r]), fmaxf(sa[2][r], sa[3][r]));
        tm = fmaxf(tm, __shfl_xor(tm, 1));
        tm = fmaxf(tm, __shfl_xor(tm, 2));
        tm = fmaxf(tm, __shfl_xor(tm, 4));
        tm = fmaxf(tm, __shfl_xor(tm, 8));
        float mn = fmaxf(m_[m][r], tm);
        al[r] = __expf(m_[m][r] - mn);
        m_[m][r] = mn;
        rs[r] = 0.f;
      }
      #pragma unroll
      for (int kb = 0; kb < 4; kb++){
        #pragma unroll
        for (int r = 0; r < 4; r++){
          float p = __expf(sa[kb][r] - m_[m][r]);
          sa[kb][r] = p;
          rs[r] += p;
        }
      }
      #pragma unroll
      for (int r = 0; r < 4; r++){
        rs[r] += __shfl_xor(rs[r], 1);
        rs[r] += __shfl_xor(rs[r], 2);
        rs[r] += __shfl_xor(rs[r], 4);
        rs[r] += __shfl_xor(rs[r], 8);
        l_[m][r] = l_[m][r] * al[r] + rs[r];
      }
      #pragma unroll
      for (int db = 0; db < 8; db++){
        #pragma unroll
        for (int r = 0; r < 4; r++) o[m][db][r] *= al[r];
      }
      #pragma unroll
      for (int kb = 0; kb < 4; kb++){
        #pragma unroll
        for (int r = 0; r < 4; r++)
          Pl[w][l4 * 4 + r][kb * 16 + l15] = f2bf(sa[kb][r]);
      }
      bf16x8 pf0 = *(const bf16x8*)&Pl[w][l15][l4 * 8];
      bf16x8 pf1 = *(const bf16x8*)&Pl[w][l15][32 + l4 * 8];
      #pragma unroll
      for (int db = 0; db < 8; db++){
        f32x4 acc = o[m][db];
        bf16x8 vf0 = *(const bf16x8*)&Vt[db * 16 + l15][l4 * 8];
        acc = __builtin_amdgcn_mfma_f32_16x16x32_bf16(pf0, vf0, acc, 0, 0, 0);
        bf16x8 vf1 = *(const bf16x8*)&Vt[db * 16 + l15][32 + l4 * 8];
        acc = __builtin_amdgcn_mfma_f32_16x16x32_bf16(pf1, vf1, acc, 0, 0, 0);
        o[m][db] = acc;
      }
    }
  }
  #pragma unroll
  for (int m = 0; m < 2; m++){
    float li[4];
    #pragma unroll
    for (int r = 0; r < 4; r++) li[r] = 1.0f / l_[m][r];
    #pragma unroll
    for (int db = 0; db < 8; db++){
      #pragma unroll
      for (int r = 0; r < 4; r++){
        size_t idx = ((size_t)b * S_ + qt * 32 + m * 16 + l4 * 4 + r) * (size_t)D_ + h * HD_ + db * 16 + l15;
        outb[idx] = f2bf(o[m][db][r] * li[r]);
      }
    }
  }
}

extern "C" void kernel_launch(void* const* d_in, const int* in_sizes, int n_in,
                              void* d_out, int out_size, void* d_ws, size_t ws_size,
                              hipStream_t stream){
  const float* x  = (const float*)d_in[0];
  const float* Wq = (const float*)d_in[1];
  const float* bq = (const float*)d_in[2];
  const float* Wk = (const float*)d_in[3];
  const float* bk = (const float*)d_in[4];
  const float* Wv = (const float*)d_in[5];
  const float* bv = (const float*)d_in[6];
  const float* Wo = (const float*)d_in[7];
  const float* bo = (const float*)d_in[8];
  const float* qn = (const float*)d_in[9];
  const float* kn = (const float*)d_in[10];
  float* out = (float*)d_out;

  char* ws = (char*)d_ws;
  unsigned short* xb    = (unsigned short*)(ws + 0);          // 16,777,216 B
  unsigned short* wqkvT = (unsigned short*)(ws + 16777216);   // 12,582,912 B
  unsigned short* woT   = (unsigned short*)(ws + 29360128);   //  8,388,608 B
  unsigned short* qkv   = (unsigned short*)(ws + 37748736);   // 25,165,824 B
  unsigned short* attnO = (unsigned short*)(ws + 62914560);   // 16,777,216 B
  unsigned short* vt    = (unsigned short*)(ws + 79691776);   //  4,194,304 B

  cvt_bf16<<<8192, 256, 0, stream>>>(x, xb);
  transpose_cvt<<<dim3(32, 32), 256, 0, stream>>>(Wq, wqkvT, 2048, 0);
  transpose_cvt<<<dim3(8, 32),  256, 0, stream>>>(Wk, wqkvT, 512, 2048);
  transpose_cvt<<<dim3(8, 32),  256, 0, stream>>>(Wv, wqkvT, 512, 2560);
  transpose_cvt<<<dim3(32, 32), 256, 0, stream>>>(Wo, woT, 2048, 0);
  gemm_bt<1><<<dim3(24, 32), 256, 0, stream>>>(xb, wqkvT, bq, bk, bv, (void*)qkv, 4096, 3072, 2048);
  rmsrope<<<20480, 256, 0, stream>>>(qkv, qn, kn);
  vtrans<<<dim3(16, 2, 16), 256, 0, stream>>>(qkv, vt);
  attn<<<dim3(32, 4, 4), 256, 0, stream>>>(qkv, vt, attnO);
  gemm_bt<0><<<dim3(16, 32), 256, 0, stream>>>(attnO, woT, bo, nullptr, nullptr, (void*)out, 4096, 2048, 2048);
}

// Round 3
// 251.397 us; speedup vs baseline: 1.3301x; 1.1350x over previous
//
#include <hip/hip_runtime.h>
#include <hip/hip_bf16.h>

#define B_ 4
#define S_ 1024
#define D_ 2048
#define H_ 16
#define G_ 4
#define HD_ 128
#define NQKV_ 3072
#define SCALE_ 0.08838834764831845f
#define EPS_ 1e-6f

typedef __attribute__((ext_vector_type(8))) short bf16x8;
typedef __attribute__((ext_vector_type(4))) float f32x4;

__device__ __forceinline__ float bf2f(unsigned short u){
  union { unsigned int i; float f; } v; v.i = ((unsigned int)u) << 16; return v.f;
}
__device__ __forceinline__ unsigned short f2bf(float f){
  union { float f; unsigned int i; } v; v.f = f;
  unsigned int x = v.i;
  return (unsigned short)((x + 0x7fffu + ((x >> 16) & 1u)) >> 16);
}
__device__ __forceinline__ void gld16(unsigned short* lds, const unsigned short* g){
  __builtin_amdgcn_global_load_lds(
      (const __attribute__((address_space(1))) unsigned int*)g,
      (__attribute__((address_space(3))) unsigned int*)lds, 16, 0, 0);
}

// ---------------- x -> bf16 ----------------
__global__ void cvt_bf16(const float* __restrict__ src, unsigned short* __restrict__ dst){
  int i = blockIdx.x * 256 + threadIdx.x;
  const float4 v = ((const float4*)src)[i];
  ushort4 o;
  o.x = f2bf(v.x); o.y = f2bf(v.y); o.z = f2bf(v.z); o.w = f2bf(v.w);
  ((ushort4*)dst)[i] = o;
}

// ---------------- W (KxN f32) -> Wt (NxK bf16), dst row stride 2048 ----------------
__global__ void transpose_cvt(const float* __restrict__ src, unsigned short* __restrict__ dst,
                              int N, int rowoff){
  __shared__ float tile[64][65];
  const int n0 = blockIdx.x * 64, k0 = blockIdx.y * 64;
  const int c = threadIdx.x & 63, rb = threadIdx.x >> 6;
  #pragma unroll
  for (int j = 0; j < 16; j++){
    int r = rb + j * 4;
    tile[r][c] = src[(size_t)(k0 + r) * N + n0 + c];
  }
  __syncthreads();
  #pragma unroll
  for (int j = 0; j < 16; j++){
    int r = rb + j * 4;
    dst[(size_t)(n0 + r + rowoff) * 2048 + k0 + c] = f2bf(tile[c][r]);
  }
}

// ---------------- GEMM: C[M][N] = A[M][K] @ Bt[N][K]^T + bias ----------------
// global_load_lds staging (m97 structure): linear LDS [128][32], BK=32.
// MODE 1: write bf16, qkv bias select (bq|bk|bv). MODE 0: write f32, bias b0.
template<int MODE>
__global__ __launch_bounds__(256, 2) void gemm_bt(const unsigned short* __restrict__ A,
    const unsigned short* __restrict__ Bt,
    const float* __restrict__ b0, const float* __restrict__ b1, const float* __restrict__ b2,
    void* __restrict__ Cout, int M, int N, int K){
  const int tid = threadIdx.x, wid = tid >> 6, lane = tid & 63;
  const int l15 = lane & 15, l4 = lane >> 4;
  const int bm = blockIdx.y * 128, bn = blockIdx.x * 128;
  const int wr = wid >> 1, wc = wid & 1;
  __shared__ __align__(16) unsigned short As[128 * 32];
  __shared__ __align__(16) unsigned short Bs[128 * 32];

  const int srow = wid * 32 + (lane >> 2);
  const int scol = (lane & 3) * 8;
  const unsigned short* pa0 = A  + (size_t)(bm + srow) * K + scol;
  const unsigned short* pa1 = pa0 + (size_t)16 * K;
  const unsigned short* pb0 = Bt + (size_t)(bn + srow) * K + scol;
  const unsigned short* pb1 = pb0 + (size_t)16 * K;
  unsigned short* la0 = As + wid * 1024;
  unsigned short* la1 = la0 + 512;
  unsigned short* lb0 = Bs + wid * 1024;
  unsigned short* lb1 = lb0 + 512;

  f32x4 acc[4][4];
  #pragma unroll
  for (int m2 = 0; m2 < 4; m2++)
    #pragma unroll
    for (int n2 = 0; n2 < 4; n2++) acc[m2][n2] = (f32x4){0.f, 0.f, 0.f, 0.f};

  for (int k0 = 0; k0 < K; k0 += 32){
    __syncthreads();
    gld16(la0, pa0 + k0);
    gld16(la1, pa1 + k0);
    gld16(lb0, pb0 + k0);
    gld16(lb1, pb1 + k0);
    __syncthreads();
    bf16x8 af[4], bfr[4];
    #pragma unroll
    for (int m2 = 0; m2 < 4; m2++) af[m2] = *(const bf16x8*)&As[(wr * 64 + m2 * 16 + l15) * 32 + l4 * 8];
    #pragma unroll
    for (int n2 = 0; n2 < 4; n2++) bfr[n2] = *(const bf16x8*)&Bs[(wc * 64 + n2 * 16 + l15) * 32 + l4 * 8];
    #pragma unroll
    for (int m2 = 0; m2 < 4; m2++)
      #pragma unroll
      for (int n2 = 0; n2 < 4; n2++)
        acc[m2][n2] = __builtin_amdgcn_mfma_f32_16x16x32_bf16(af[m2], bfr[n2], acc[m2][n2], 0, 0, 0);
  }
  #pragma unroll
  for (int m2 = 0; m2 < 4; m2++)
    #pragma unroll
    for (int n2 = 0; n2 < 4; n2++){
      int col = bn + wc * 64 + n2 * 16 + l15;
      float bias;
      if (MODE == 1) bias = col < 2048 ? b0[col] : (col < 2560 ? b1[col - 2048] : b2[col - 2560]);
      else           bias = b0[col];
      #pragma unroll
      for (int r = 0; r < 4; r++){
        int row = bm + wr * 64 + m2 * 16 + l4 * 4 + r;
        float v = acc[m2][n2][r] + bias;
        if (MODE == 1) ((unsigned short*)Cout)[(size_t)row * N + col] = f2bf(v);
        else           ((float*)Cout)[(size_t)row * N + col] = v;
      }
    }
}

// ---------------- fused RMSNorm + RoPE, in place on q/k parts of qkv ----------------
__global__ void rmsrope(unsigned short* __restrict__ qkv, const float* __restrict__ qn,
                        const float* __restrict__ kn){
  const int w = blockIdx.x * 4 + (threadIdx.x >> 6);
  const int lane = threadIdx.x & 63;
  const int t = w / 20, sub = w % 20;
  const int s = t & (S_ - 1);
  const bool isq = sub < 16;
  unsigned short* row;
  const float* sc;
  if (isq){ row = qkv + (size_t)t * NQKV_ + sub * HD_; sc = qn; }
  else    { row = qkv + (size_t)t * NQKV_ + 2048 + (sub - 16) * HD_; sc = kn; }
  unsigned int pr = *(const unsigned int*)&row[2 * lane];
  float xe = bf2f((unsigned short)(pr & 0xffffu));
  float xo = bf2f((unsigned short)(pr >> 16));
  float ss = xe * xe + xo * xo;
  #pragma unroll
  for (int o = 1; o < 64; o <<= 1) ss += __shfl_xor(ss, o);
  float rn = rsqrtf(ss * (1.0f / 128.0f) + EPS_);
  xe = xe * rn * sc[2 * lane];
  xo = xo * rn * sc[2 * lane + 1];
  float inv = powf(10000.0f, -(float)lane * (1.0f / 64.0f));
  float th = (float)s * inv;
  float sn = sinf(th), cs = cosf(th);
  float oe = xe * cs - xo * sn;
  float oo = xe * sn + xo * cs;
  if (isq){ oe *= SCALE_; oo *= SCALE_; }
  *(unsigned int*)&row[2 * lane] = (unsigned int)f2bf(oe) | ((unsigned int)f2bf(oo) << 16);
}

// ---------------- V -> V^T per (b,g): vt[(bg*128+d)*1024 + s] ----------------
__global__ void vtrans(const unsigned short* __restrict__ qkv, unsigned short* __restrict__ vt){
  __shared__ unsigned short tile[64][65];
  const int s0 = blockIdx.x * 64, d0 = blockIdx.y * 64;
  const int bg = blockIdx.z, b = bg >> 2, g = bg & 3;
  const int c = threadIdx.x & 63, rb = threadIdx.x >> 6;
  #pragma unroll
  for (int j = 0; j < 16; j++){
    int r = rb + j * 4;
    tile[r][c] = qkv[((size_t)b * S_ + s0 + r) * NQKV_ + 2560 + g * HD_ + d0 + c];
  }
  __syncthreads();
  #pragma unroll
  for (int j = 0; j < 16; j++){
    int r = rb + j * 4;
    vt[((size_t)bg * HD_ + d0 + r) * (size_t)S_ + s0 + c] = tile[c][r];
  }
}

// ---------------- flash attention, MFMA, causal GQA ----------------
// block = (32 q-rows, g, b); 4 waves = 4 heads of group g.
// 2-phase double-buffered K/V staging via global_load_lds, XOR-swizzled LDS
// (linear dest + inverse-swizzled global source + swizzled ds_read, rule #21).
__global__ __launch_bounds__(256, 2) void attn(const unsigned short* __restrict__ qkv,
    const unsigned short* __restrict__ vt, unsigned short* __restrict__ outb){
  const int qt = 31 - blockIdx.x;            // big (late-diagonal) blocks dispatch first
  const int g = blockIdx.y, b = blockIdx.z;
  const int tid = threadIdx.x, w = tid >> 6, lane = tid & 63;
  const int h = g * 4 + w;
  const int l15 = lane & 15, l4 = lane >> 4;
  const int nkt = qt / 2 + 1;
  __shared__ __align__(16) unsigned short Ks[2][64 * 128];  // swizzled: byte ^= (row&7)<<4
  __shared__ __align__(16) unsigned short Vs[2][128 * 64];  // swizzled: byte ^= (row&7)<<4
  __shared__ __align__(16) unsigned short Pl[4][16][72];

  // staging: per wave, K rows [w*16, w*16+16) in 4 gld16; V rows [w*32, w*32+32) in 4 gld16.
  // lane -> (row, within-row 16B chunk), global source pre-applies the XOR swizzle.
  #define STAGE_KV(BF, KT)                                                              \
    do {                                                                                \
      _Pragma("unroll")                                                                 \
      for (int i_ = 0; i_ < 4; i_++){                                                   \
        int row_ = w * 16 + i_ * 4 + (lane >> 4);                                       \
        const unsigned short* src_ = qkv + (size_t)(b * S_ + (KT) * 64 + row_) * NQKV_  \
            + 2048 + g * HD_ + (((lane & 15) * 8) ^ ((row_ & 7) << 3));                 \
        gld16(&Ks[BF][(w * 16 + i_ * 4) * 128], src_);                                  \
      }                                                                                 \
      _Pragma("unroll")                                                                 \
      for (int i_ = 0; i_ < 4; i_++){                                                   \
        int row_ = w * 32 + i_ * 8 + (lane >> 3);                                       \
        const unsigned short* src_ = vt + (size_t)((b * G_ + g) * HD_ + row_) * S_      \
            + (KT) * 64 + (((lane & 7) * 8) ^ ((row_ & 7) << 3));                       \
        gld16(&Vs[BF][(w * 32 + i_ * 8) * 64], src_);                                   \
      }                                                                                 \
    } while (0)

  bf16x8 qf[2][4];
  #pragma unroll
  for (int m = 0; m < 2; m++){
    const size_t qbase = ((size_t)b * S_ + qt * 32 + m * 16 + l15) * NQKV_ + h * HD_;
    #pragma unroll
    for (int c = 0; c < 4; c++) qf[m][c] = *(const bf16x8*)&qkv[qbase + c * 32 + l4 * 8];
  }
  f32x4 o[2][8];
  #pragma unroll
  for (int m = 0; m < 2; m++)
    #pragma unroll
    for (int i = 0; i < 8; i++) o[m][i] = (f32x4){0.f, 0.f, 0.f, 0.f};
  float m_[2][4], l_[2][4];
  #pragma unroll
  for (int m = 0; m < 2; m++)
    #pragma unroll
    for (int r = 0; r < 4; r++){ m_[m][r] = -1e30f; l_[m][r] = 0.f; }

  int bf = 0;
  STAGE_KV(0, 0);
  __syncthreads();

  for (int kt = 0; kt < nkt; ++kt){
    if (kt + 1 < nkt){
      if (bf) STAGE_KV(0, kt + 1); else STAGE_KV(1, kt + 1);
    }
    const unsigned short* KB = Ks[bf];
    const unsigned short* VB = Vs[bf];
    // hoisted K fragments (shared across both m-subtiles), swizzled read
    bf16x8 kf[4][4];
    #pragma unroll
    for (int kb = 0; kb < 4; kb++)
      #pragma unroll
      for (int c = 0; c < 4; c++)
        kf[kb][c] = *(const bf16x8*)&KB[(kb * 16 + l15) * 128 + ((c * 32 + l4 * 8) ^ ((l15 & 7) << 3))];
    const bool diag = (kt == nkt - 1);

    #pragma unroll
    for (int m = 0; m < 2; m++){
      f32x4 sa[4];
      __builtin_amdgcn_s_setprio(1);
      #pragma unroll
      for (int kb = 0; kb < 4; kb++){
        f32x4 acc = (f32x4){0.f, 0.f, 0.f, 0.f};
        #pragma unroll
        for (int c = 0; c < 4; c++)
          acc = __builtin_amdgcn_mfma_f32_16x16x32_bf16(qf[m][c], kf[kb][c], acc, 0, 0, 0);
        sa[kb] = acc;
      }
      __builtin_amdgcn_s_setprio(0);
      if (diag){
        #pragma unroll
        for (int kb = 0; kb < 4; kb++){
          #pragma unroll
          for (int r = 0; r < 4; r++){
            float v = sa[kb][r] * SCALE_;
            int key = kt * 64 + kb * 16 + l15;
            int qrow = qt * 32 + m * 16 + l4 * 4 + r;
            sa[kb][r] = (key > qrow) ? -1e30f : v;
          }
        }
      } else {
        #pragma unroll
        for (int kb = 0; kb < 4; kb++)
          #pragma unroll
          for (int r = 0; r < 4; r++) sa[kb][r] *= SCALE_;
      }
      float al[4], rs[4];
      #pragma unroll
      for (int r = 0; r < 4; r++){
        float tm = fmaxf(fmaxf(sa[0][r], sa[1][r]), fmaxf(sa[2][r], sa[3][r]));
        tm = fmaxf(tm, __shfl_xor(tm, 1));
        tm = fmaxf(tm, __shfl_xor(tm, 2));
        tm = fmaxf(tm, __shfl_xor(tm, 4));
        tm = fmaxf(tm, __shfl_xor(tm, 8));
        float mn = fmaxf(m_[m][r], tm);
        al[r] = __expf(m_[m][r] - mn);
        m_[m][r] = mn;
        rs[r] = 0.f;
      }
      #pragma unroll
      for (int kb = 0; kb < 4; kb++){
        #pragma unroll
        for (int r = 0; r < 4; r++){
          float p = __expf(sa[kb][r] - m_[m][r]);
          sa[kb][r] = p;
          rs[r] += p;
        }
      }
      #pragma unroll
      for (int r = 0; r < 4; r++){
        rs[r] += __shfl_xor(rs[r], 1);
        rs[r] += __shfl_xor(rs[r], 2);
        rs[r] += __shfl_xor(rs[r], 4);
        rs[r] += __shfl_xor(rs[r], 8);
        l_[m][r] = l_[m][r] * al[r] + rs[r];
      }
      #pragma unroll
      for (int db = 0; db < 8; db++){
        #pragma unroll
        for (int r = 0; r < 4; r++) o[m][db][r] *= al[r];
      }
      #pragma unroll
      for (int kb = 0; kb < 4; kb++){
        #pragma unroll
        for (int r = 0; r < 4; r++)
          Pl[w][l4 * 4 + r][kb * 16 + l15] = f2bf(sa[kb][r]);
      }
      bf16x8 pf0 = *(const bf16x8*)&Pl[w][l15][l4 * 8];
      bf16x8 pf1 = *(const bf16x8*)&Pl[w][l15][32 + l4 * 8];
      __builtin_amdgcn_s_setprio(1);
      #pragma unroll
      for (int db = 0; db < 8; db++){
        f32x4 acc = o[m][db];
        bf16x8 vf0 = *(const bf16x8*)&VB[(db * 16 + l15) * 64 + ((l4 * 8) ^ ((l15 & 7) << 3))];
        acc = __builtin_amdgcn_mfma_f32_16x16x32_bf16(pf0, vf0, acc, 0, 0, 0);
        bf16x8 vf1 = *(const bf16x8*)&VB[(db * 16 + l15) * 64 + ((32 + l4 * 8) ^ ((l15 & 7) << 3))];
        acc = __builtin_amdgcn_mfma_f32_16x16x32_bf16(pf1, vf1, acc, 0, 0, 0);
        o[m][db] = acc;
      }
      __builtin_amdgcn_s_setprio(0);
    }
    __syncthreads();
    bf ^= 1;
  }
  #pragma unroll
  for (int m = 0; m < 2; m++){
    float li[4];
    #pragma unroll
    for (int r = 0; r < 4; r++) li[r] = 1.0f / l_[m][r];
    #pragma unroll
    for (int db = 0; db < 8; db++){
      #pragma unroll
      for (int r = 0; r < 4; r++){
        size_t idx = ((size_t)b * S_ + qt * 32 + m * 16 + l4 * 4 + r) * (size_t)D_ + h * HD_ + db * 16 + l15;
        outb[idx] = f2bf(o[m][db][r] * li[r]);
      }
    }
  }
  #undef STAGE_KV
}

extern "C" void kernel_launch(void* const* d_in, const int* in_sizes, int n_in,
                              void* d_out, int out_size, void* d_ws, size_t ws_size,
                              hipStream_t stream){
  const float* x  = (const float*)d_in[0];
  const float* Wq = (const float*)d_in[1];
  const float* bq = (const float*)d_in[2];
  const float* Wk = (const float*)d_in[3];
  const float* bk = (const float*)d_in[4];
  const float* Wv = (const float*)d_in[5];
  const float* bv = (const float*)d_in[6];
  const float* Wo = (const float*)d_in[7];
  const float* bo = (const float*)d_in[8];
  const float* qn = (const float*)d_in[9];
  const float* kn = (const float*)d_in[10];
  float* out = (float*)d_out;

  char* ws = (char*)d_ws;
  unsigned short* xb    = (unsigned short*)(ws + 0);          // 16,777,216 B
  unsigned short* wqkvT = (unsigned short*)(ws + 16777216);   // 12,582,912 B
  unsigned short* woT   = (unsigned short*)(ws + 29360128);   //  8,388,608 B
  unsigned short* qkv   = (unsigned short*)(ws + 37748736);   // 25,165,824 B
  unsigned short* attnO = (unsigned short*)(ws + 62914560);   // 16,777,216 B
  unsigned short* vt    = (unsigned short*)(ws + 79691776);   //  4,194,304 B

  cvt_bf16<<<8192, 256, 0, stream>>>(x, xb);
  transpose_cvt<<<dim3(32, 32), 256, 0, stream>>>(Wq, wqkvT, 2048, 0);
  transpose_cvt<<<dim3(8, 32),  256, 0, stream>>>(Wk, wqkvT, 512, 2048);
  transpose_cvt<<<dim3(8, 32),  256, 0, stream>>>(Wv, wqkvT, 512, 2560);
  transpose_cvt<<<dim3(32, 32), 256, 0, stream>>>(Wo, woT, 2048, 0);
  gemm_bt<1><<<dim3(24, 32), 256, 0, stream>>>(xb, wqkvT, bq, bk, bv, (void*)qkv, 4096, 3072, 2048);
  rmsrope<<<20480, 256, 0, stream>>>(qkv, qn, kn);
  vtrans<<<dim3(16, 2, 16), 256, 0, stream>>>(qkv, vt);
  attn<<<dim3(32, 4, 4), 256, 0, stream>>>(qkv, vt, attnO);
  gemm_bt<0><<<dim3(16, 32), 256, 0, stream>>>(attnO, woT, bo, nullptr, nullptr, (void*)out, 4096, 2048, 2048);
}

// Round 4
// 245.913 us; speedup vs baseline: 1.3598x; 1.0223x over previous
//
#include <hip/hip_runtime.h>
#include <hip/hip_bf16.h>

#define B_ 4
#define S_ 1024
#define D_ 2048
#define H_ 16
#define G_ 4
#define HD_ 128
#define NQKV_ 3072
#define SCALE_ 0.08838834764831845f
#define EPS_ 1e-6f

typedef __attribute__((ext_vector_type(8))) short bf16x8;
typedef __attribute__((ext_vector_type(4))) float f32x4;

__device__ __forceinline__ float bf2f(unsigned short u){
  union { unsigned int i; float f; } v; v.i = ((unsigned int)u) << 16; return v.f;
}
__device__ __forceinline__ unsigned short f2bf(float f){
  union { float f; unsigned int i; } v; v.f = f;
  unsigned int x = v.i;
  return (unsigned short)((x + 0x7fffu + ((x >> 16) & 1u)) >> 16);
}
__device__ __forceinline__ void gld16(unsigned short* lds, const unsigned short* g){
  __builtin_amdgcn_global_load_lds(
      (const __attribute__((address_space(1))) unsigned int*)g,
      (__attribute__((address_space(3))) unsigned int*)lds, 16, 0, 0);
}

// ---------------- x -> bf16 ----------------
__global__ void cvt_bf16(const float* __restrict__ src, unsigned short* __restrict__ dst){
  int i = blockIdx.x * 256 + threadIdx.x;
  const float4 v = ((const float4*)src)[i];
  ushort4 o;
  o.x = f2bf(v.x); o.y = f2bf(v.y); o.z = f2bf(v.z); o.w = f2bf(v.w);
  ((ushort4*)dst)[i] = o;
}

// ---------------- W (KxN f32) -> Wt (NxK bf16), dst row stride 2048 ----------------
__global__ void transpose_cvt(const float* __restrict__ src, unsigned short* __restrict__ dst,
                              int N, int rowoff){
  __shared__ float tile[64][65];
  const int n0 = blockIdx.x * 64, k0 = blockIdx.y * 64;
  const int c = threadIdx.x & 63, rb = threadIdx.x >> 6;
  #pragma unroll
  for (int j = 0; j < 16; j++){
    int r = rb + j * 4;
    tile[r][c] = src[(size_t)(k0 + r) * N + n0 + c];
  }
  __syncthreads();
  #pragma unroll
  for (int j = 0; j < 16; j++){
    int r = rb + j * 4;
    dst[(size_t)(n0 + r + rowoff) * 2048 + k0 + c] = f2bf(tile[c][r]);
  }
}

// ---------------- GEMM: C[M][N] = A[M][K] @ Bt[N][K]^T + bias ----------------
// global_load_lds staging (m97 structure): linear LDS [128][32], BK=32.
// MODE 1: write bf16, qkv bias select (bq|bk|bv). MODE 0: write f32, bias b0.
template<int MODE>
__global__ __launch_bounds__(256, 2) void gemm_bt(const unsigned short* __restrict__ A,
    const unsigned short* __restrict__ Bt,
    const float* __restrict__ b0, const float* __restrict__ b1, const float* __restrict__ b2,
    void* __restrict__ Cout, int M, int N, int K){
  const int tid = threadIdx.x, wid = tid >> 6, lane = tid & 63;
  const int l15 = lane & 15, l4 = lane >> 4;
  const int bm = blockIdx.y * 128, bn = blockIdx.x * 128;
  const int wr = wid >> 1, wc = wid & 1;
  __shared__ __align__(16) unsigned short As[128 * 32];
  __shared__ __align__(16) unsigned short Bs[128 * 32];

  const int srow = wid * 32 + (lane >> 2);
  const int scol = (lane & 3) * 8;
  const unsigned short* pa0 = A  + (size_t)(bm + srow) * K + scol;
  const unsigned short* pa1 = pa0 + (size_t)16 * K;
  const unsigned short* pb0 = Bt + (size_t)(bn + srow) * K + scol;
  const unsigned short* pb1 = pb0 + (size_t)16 * K;
  unsigned short* la0 = As + wid * 1024;
  unsigned short* la1 = la0 + 512;
  unsigned short* lb0 = Bs + wid * 1024;
  unsigned short* lb1 = lb0 + 512;

  f32x4 acc[4][4];
  #pragma unroll
  for (int m2 = 0; m2 < 4; m2++)
    #pragma unroll
    for (int n2 = 0; n2 < 4; n2++) acc[m2][n2] = (f32x4){0.f, 0.f, 0.f, 0.f};

  for (int k0 = 0; k0 < K; k0 += 32){
    __syncthreads();
    gld16(la0, pa0 + k0);
    gld16(la1, pa1 + k0);
    gld16(lb0, pb0 + k0);
    gld16(lb1, pb1 + k0);
    __syncthreads();
    bf16x8 af[4], bfr[4];
    #pragma unroll
    for (int m2 = 0; m2 < 4; m2++) af[m2] = *(const bf16x8*)&As[(wr * 64 + m2 * 16 + l15) * 32 + l4 * 8];
    #pragma unroll
    for (int n2 = 0; n2 < 4; n2++) bfr[n2] = *(const bf16x8*)&Bs[(wc * 64 + n2 * 16 + l15) * 32 + l4 * 8];
    #pragma unroll
    for (int m2 = 0; m2 < 4; m2++)
      #pragma unroll
      for (int n2 = 0; n2 < 4; n2++)
        acc[m2][n2] = __builtin_amdgcn_mfma_f32_16x16x32_bf16(af[m2], bfr[n2], acc[m2][n2], 0, 0, 0);
  }
  #pragma unroll
  for (int m2 = 0; m2 < 4; m2++)
    #pragma unroll
    for (int n2 = 0; n2 < 4; n2++){
      int col = bn + wc * 64 + n2 * 16 + l15;
      float bias;
      if (MODE == 1) bias = col < 2048 ? b0[col] : (col < 2560 ? b1[col - 2048] : b2[col - 2560]);
      else           bias = b0[col];
      #pragma unroll
      for (int r = 0; r < 4; r++){
        int row = bm + wr * 64 + m2 * 16 + l4 * 4 + r;
        float v = acc[m2][n2][r] + bias;
        if (MODE == 1) ((unsigned short*)Cout)[(size_t)row * N + col] = f2bf(v);
        else           ((float*)Cout)[(size_t)row * N + col] = v;
      }
    }
}

// ---------------- fused RMSNorm + RoPE, in place on q/k parts of qkv ----------------
__global__ void rmsrope(unsigned short* __restrict__ qkv, const float* __restrict__ qn,
                        const float* __restrict__ kn){
  const int w = blockIdx.x * 4 + (threadIdx.x >> 6);
  const int lane = threadIdx.x & 63;
  const int t = w / 20, sub = w % 20;
  const int s = t & (S_ - 1);
  const bool isq = sub < 16;
  unsigned short* row;
  const float* sc;
  if (isq){ row = qkv + (size_t)t * NQKV_ + sub * HD_; sc = qn; }
  else    { row = qkv + (size_t)t * NQKV_ + 2048 + (sub - 16) * HD_; sc = kn; }
  unsigned int pr = *(const unsigned int*)&row[2 * lane];
  float xe = bf2f((unsigned short)(pr & 0xffffu));
  float xo = bf2f((unsigned short)(pr >> 16));
  float ss = xe * xe + xo * xo;
  #pragma unroll
  for (int o = 1; o < 64; o <<= 1) ss += __shfl_xor(ss, o);
  float rn = rsqrtf(ss * (1.0f / 128.0f) + EPS_);
  xe = xe * rn * sc[2 * lane];
  xo = xo * rn * sc[2 * lane + 1];
  // 10000^(-lane/64) = exp2(-lane * log2(10000)/64); v_exp_f32 single-instr
  float inv = exp2f((float)lane * -0.20762051f);
  float th = (float)s * inv;                 // max 1023 rad = 163 rev < 256 (HW-valid)
  float sn = __sinf(th), cs = __cosf(th);
  float oe = xe * cs - xo * sn;
  float oo = xe * sn + xo * cs;
  if (isq){ oe *= SCALE_; oo *= SCALE_; }
  *(unsigned int*)&row[2 * lane] = (unsigned int)f2bf(oe) | ((unsigned int)f2bf(oo) << 16);
}

// ---------------- V -> V^T per (b,g): vt[(bg*128+d)*1024 + s] ----------------
__global__ void vtrans(const unsigned short* __restrict__ qkv, unsigned short* __restrict__ vt){
  __shared__ unsigned short tile[64][65];
  const int s0 = blockIdx.x * 64, d0 = blockIdx.y * 64;
  const int bg = blockIdx.z, b = bg >> 2, g = bg & 3;
  const int c = threadIdx.x & 63, rb = threadIdx.x >> 6;
  #pragma unroll
  for (int j = 0; j < 16; j++){
    int r = rb + j * 4;
    tile[r][c] = qkv[((size_t)b * S_ + s0 + r) * NQKV_ + 2560 + g * HD_ + d0 + c];
  }
  __syncthreads();
  #pragma unroll
  for (int j = 0; j < 16; j++){
    int r = rb + j * 4;
    vt[((size_t)bg * HD_ + d0 + r) * (size_t)S_ + s0 + c] = tile[c][r];
  }
}

// ---------------- flash attention, MFMA, causal GQA ----------------
// block = (32 q-rows, g, b); 4 waves = 4 heads of group g.
// K double-buffered in swizzled LDS via global_load_lds; V read direct from
// global (L2-resident); P via wave-private LDS. 1-D grid with XCD-aware
// mapping: each XCD owns 2 (b,g) groups so its L2 caches only their K/V.
__global__ __launch_bounds__(256, 4) void attn(const unsigned short* __restrict__ qkv,
    const unsigned short* __restrict__ vt, unsigned short* __restrict__ outb){
  const int bid = blockIdx.x;
  const int j = bid >> 3;
  const int gb = (bid & 7) * 2 + (j >> 5);
  const int qt = 31 - (j & 31);              // big (late-diagonal) blocks first
  const int g = gb & 3, b = gb >> 2;
  const int tid = threadIdx.x, w = tid >> 6, lane = tid & 63;
  const int h = g * 4 + w;
  const int l15 = lane & 15, l4 = lane >> 4;
  const int nkt = qt / 2 + 1;
  __shared__ __align__(16) unsigned short Ks[2][64 * 128];  // swizzled: col ^= (row&7)<<3
  __shared__ __align__(16) unsigned short Pl[4][32][72];    // per-wave P (both m halves)

  #define STAGE_K(BF, KT)                                                               \
    do {                                                                                \
      _Pragma("unroll")                                                                 \
      for (int i_ = 0; i_ < 4; i_++){                                                   \
        int row_ = w * 16 + i_ * 4 + (lane >> 4);                                       \
        const unsigned short* src_ = qkv + (size_t)(b * S_ + (KT) * 64 + row_) * NQKV_  \
            + 2048 + g * HD_ + (((lane & 15) * 8) ^ ((row_ & 7) << 3));                 \
        gld16(&Ks[BF][(w * 16 + i_ * 4) * 128], src_);                                  \
      }                                                                                 \
    } while (0)

  bf16x8 qf[2][4];
  #pragma unroll
  for (int m = 0; m < 2; m++){
    const size_t qbase = ((size_t)b * S_ + qt * 32 + m * 16 + l15) * NQKV_ + h * HD_;
    #pragma unroll
    for (int c = 0; c < 4; c++) qf[m][c] = *(const bf16x8*)&qkv[qbase + c * 32 + l4 * 8];
  }
  f32x4 o[2][8];
  #pragma unroll
  for (int m = 0; m < 2; m++)
    #pragma unroll
    for (int i = 0; i < 8; i++) o[m][i] = (f32x4){0.f, 0.f, 0.f, 0.f};
  float m_[2][4], l_[2][4];
  #pragma unroll
  for (int m = 0; m < 2; m++)
    #pragma unroll
    for (int r = 0; r < 4; r++){ m_[m][r] = -1e30f; l_[m][r] = 0.f; }

  int bf = 0;
  STAGE_K(0, 0);
  __syncthreads();
  const unsigned short* vbase = vt + ((size_t)(b * G_ + g) * HD_ + l15) * S_ + l4 * 8;

  for (int kt = 0; kt < nkt; ++kt){
    if (kt + 1 < nkt){
      if (bf) STAGE_K(0, kt + 1); else STAGE_K(1, kt + 1);
    }
    const unsigned short* KB = Ks[bf];
    const bool diag = (kt == nkt - 1);

    // ---- QK^T: K fragments shared across both m sub-tiles ----
    f32x4 sa[2][4];
    #pragma unroll
    for (int kb = 0; kb < 4; kb++){
      bf16x8 kf[4];
      #pragma unroll
      for (int c = 0; c < 4; c++)
        kf[c] = *(const bf16x8*)&KB[(kb * 16 + l15) * 128 + ((c * 32 + l4 * 8) ^ ((l15 & 7) << 3))];
      __builtin_amdgcn_s_setprio(1);
      #pragma unroll
      for (int m = 0; m < 2; m++){
        f32x4 acc = (f32x4){0.f, 0.f, 0.f, 0.f};
        #pragma unroll
        for (int c = 0; c < 4; c++)
          acc = __builtin_amdgcn_mfma_f32_16x16x32_bf16(qf[m][c], kf[c], acc, 0, 0, 0);
        sa[m][kb] = acc;
      }
      __builtin_amdgcn_s_setprio(0);
    }

    // ---- per-m online softmax + P store (wave-private LDS, no barrier) ----
    #pragma unroll
    for (int m = 0; m < 2; m++){
      if (diag){
        #pragma unroll
        for (int kb = 0; kb < 4; kb++){
          #pragma unroll
          for (int r = 0; r < 4; r++){
            float v = sa[m][kb][r] * SCALE_;
            int key = kt * 64 + kb * 16 + l15;
            int qrow = qt * 32 + m * 16 + l4 * 4 + r;
            sa[m][kb][r] = (key > qrow) ? -1e30f : v;
          }
        }
      } else {
        #pragma unroll
        for (int kb = 0; kb < 4; kb++)
          #pragma unroll
          for (int r = 0; r < 4; r++) sa[m][kb][r] *= SCALE_;
      }
      float al[4], rs[4];
      #pragma unroll
      for (int r = 0; r < 4; r++){
        float tm = fmaxf(fmaxf(sa[m][0][r], sa[m][1][r]), fmaxf(sa[m][2][r], sa[m][3][r]));
        tm = fmaxf(tm, __shfl_xor(tm, 1));
        tm = fmaxf(tm, __shfl_xor(tm, 2));
        tm = fmaxf(tm, __shfl_xor(tm, 4));
        tm = fmaxf(tm, __shfl_xor(tm, 8));
        float mn = fmaxf(m_[m][r], tm);
        al[r] = __expf(m_[m][r] - mn);
        m_[m][r] = mn;
        rs[r] = 0.f;
      }
      #pragma unroll
      for (int kb = 0; kb < 4; kb++){
        #pragma unroll
        for (int r = 0; r < 4; r++){
          float p = __expf(sa[m][kb][r] - m_[m][r]);
          sa[m][kb][r] = p;
          rs[r] += p;
        }
      }
      #pragma unroll
      for (int r = 0; r < 4; r++){
        rs[r] += __shfl_xor(rs[r], 1);
        rs[r] += __shfl_xor(rs[r], 2);
        rs[r] += __shfl_xor(rs[r], 4);
        rs[r] += __shfl_xor(rs[r], 8);
        l_[m][r] = l_[m][r] * al[r] + rs[r];
      }
      #pragma unroll
      for (int db = 0; db < 8; db++){
        #pragma unroll
        for (int r = 0; r < 4; r++) o[m][db][r] *= al[r];
      }
      #pragma unroll
      for (int kb = 0; kb < 4; kb++){
        #pragma unroll
        for (int r = 0; r < 4; r++)
          Pl[w][m * 16 + l4 * 4 + r][kb * 16 + l15] = f2bf(sa[m][kb][r]);
      }
    }

    // ---- PV: V fragments direct from global (L2), shared across both m ----
    bf16x8 pf[2][2];
    #pragma unroll
    for (int m = 0; m < 2; m++){
      pf[m][0] = *(const bf16x8*)&Pl[w][m * 16 + l15][l4 * 8];
      pf[m][1] = *(const bf16x8*)&Pl[w][m * 16 + l15][32 + l4 * 8];
    }
    const unsigned short* vb = vbase + kt * 64;
    __builtin_amdgcn_s_setprio(1);
    #pragma unroll
    for (int db = 0; db < 8; db++){
      bf16x8 vf0 = *(const bf16x8*)&vb[(size_t)(db * 16) * S_];
      bf16x8 vf1 = *(const bf16x8*)&vb[(size_t)(db * 16) * S_ + 32];
      #pragma unroll
      for (int m = 0; m < 2; m++){
        o[m][db] = __builtin_amdgcn_mfma_f32_16x16x32_bf16(pf[m][0], vf0, o[m][db], 0, 0, 0);
        o[m][db] = __builtin_amdgcn_mfma_f32_16x16x32_bf16(pf[m][1], vf1, o[m][db], 0, 0, 0);
      }
    }
    __builtin_amdgcn_s_setprio(0);
    __syncthreads();
    bf ^= 1;
  }
  #pragma unroll
  for (int m = 0; m < 2; m++){
    float li[4];
    #pragma unroll
    for (int r = 0; r < 4; r++) li[r] = 1.0f / l_[m][r];
    #pragma unroll
    for (int db = 0; db < 8; db++){
      #pragma unroll
      for (int r = 0; r < 4; r++){
        size_t idx = ((size_t)b * S_ + qt * 32 + m * 16 + l4 * 4 + r) * (size_t)D_ + h * HD_ + db * 16 + l15;
        outb[idx] = f2bf(o[m][db][r] * li[r]);
      }
    }
  }
  #undef STAGE_K
}

extern "C" void kernel_launch(void* const* d_in, const int* in_sizes, int n_in,
                              void* d_out, int out_size, void* d_ws, size_t ws_size,
                              hipStream_t stream){
  const float* x  = (const float*)d_in[0];
  const float* Wq = (const float*)d_in[1];
  const float* bq = (const float*)d_in[2];
  const float* Wk = (const float*)d_in[3];
  const float* bk = (const float*)d_in[4];
  const float* Wv = (const float*)d_in[5];
  const float* bv = (const float*)d_in[6];
  const float* Wo = (const float*)d_in[7];
  const float* bo = (const float*)d_in[8];
  const float* qn = (const float*)d_in[9];
  const float* kn = (const float*)d_in[10];
  float* out = (float*)d_out;

  char* ws = (char*)d_ws;
  unsigned short* xb    = (unsigned short*)(ws + 0);          // 16,777,216 B
  unsigned short* wqkvT = (unsigned short*)(ws + 16777216);   // 12,582,912 B
  unsigned short* woT   = (unsigned short*)(ws + 29360128);   //  8,388,608 B
  unsigned short* qkv   = (unsigned short*)(ws + 37748736);   // 25,165,824 B
  unsigned short* attnO = (unsigned short*)(ws + 62914560);   // 16,777,216 B
  unsigned short* vt    = (unsigned short*)(ws + 79691776);   //  4,194,304 B

  cvt_bf16<<<8192, 256, 0, stream>>>(x, xb);
  transpose_cvt<<<dim3(32, 32), 256, 0, stream>>>(Wq, wqkvT, 2048, 0);
  transpose_cvt<<<dim3(8, 32),  256, 0, stream>>>(Wk, wqkvT, 512, 2048);
  transpose_cvt<<<dim3(8, 32),  256, 0, stream>>>(Wv, wqkvT, 512, 2560);
  transpose_cvt<<<dim3(32, 32), 256, 0, stream>>>(Wo, woT, 2048, 0);
  gemm_bt<1><<<dim3(24, 32), 256, 0, stream>>>(xb, wqkvT, bq, bk, bv, (void*)qkv, 4096, 3072, 2048);
  rmsrope<<<20480, 256, 0, stream>>>(qkv, qn, kn);
  vtrans<<<dim3(16, 2, 16), 256, 0, stream>>>(qkv, vt);
  attn<<<512, 256, 0, stream>>>(qkv, vt, attnO);
  gemm_bt<0><<<dim3(16, 32), 256, 0, stream>>>(attnO, woT, bo, nullptr, nullptr, (void*)out, 4096, 2048, 2048);
}

// Round 5
// 191.184 us; speedup vs baseline: 1.7491x; 1.2863x over previous
//
#include <hip/hip_runtime.h>
#include <hip/hip_bf16.h>

#define B_ 4
#define S_ 1024
#define D_ 2048
#define H_ 16
#define G_ 4
#define HD_ 128
#define NQKV_ 3072
#define SCALE_ 0.08838834764831845f
#define EPS_ 1e-6f

typedef __attribute__((ext_vector_type(8))) short bf16x8;
typedef __attribute__((ext_vector_type(4))) float f32x4;
typedef __attribute__((ext_vector_type(16))) float f32x16;

__device__ __forceinline__ float bf2f(unsigned short u){
  union { unsigned int i; float f; } v; v.i = ((unsigned int)u) << 16; return v.f;
}
__device__ __forceinline__ unsigned short f2bf(float f){
  union { float f; unsigned int i; } v; v.f = f;
  unsigned int x = v.i;
  return (unsigned short)((x + 0x7fffu + ((x >> 16) & 1u)) >> 16);
}
__device__ __forceinline__ void gld16(unsigned short* lds, const unsigned short* g){
  __builtin_amdgcn_global_load_lds(
      (const __attribute__((address_space(1))) unsigned int*)g,
      (__attribute__((address_space(3))) unsigned int*)lds, 16, 0, 0);
}

// ---------------- x -> bf16 ----------------
__global__ void cvt_bf16(const float* __restrict__ src, unsigned short* __restrict__ dst){
  int i = blockIdx.x * 256 + threadIdx.x;
  const float4 v = ((const float4*)src)[i];
  ushort4 o;
  o.x = f2bf(v.x); o.y = f2bf(v.y); o.z = f2bf(v.z); o.w = f2bf(v.w);
  ((ushort4*)dst)[i] = o;
}

// ---------------- W (KxN f32) -> Wt (NxK bf16), dst row stride 2048 ----------------
__global__ void transpose_cvt(const float* __restrict__ src, unsigned short* __restrict__ dst,
                              int N, int rowoff){
  __shared__ float tile[64][65];
  const int n0 = blockIdx.x * 64, k0 = blockIdx.y * 64;
  const int c = threadIdx.x & 63, rb = threadIdx.x >> 6;
  #pragma unroll
  for (int j = 0; j < 16; j++){
    int r = rb + j * 4;
    tile[r][c] = src[(size_t)(k0 + r) * N + n0 + c];
  }
  __syncthreads();
  #pragma unroll
  for (int j = 0; j < 16; j++){
    int r = rb + j * 4;
    dst[(size_t)(n0 + r + rowoff) * 2048 + k0 + c] = f2bf(tile[c][r]);
  }
}

// ---------------- GEMM: C[M][N] = A[M][K] @ Bt[N][K]^T + bias ----------------
template<int MODE>
__global__ __launch_bounds__(256, 2) void gemm_bt(const unsigned short* __restrict__ A,
    const unsigned short* __restrict__ Bt,
    const float* __restrict__ b0, const float* __restrict__ b1, const float* __restrict__ b2,
    void* __restrict__ Cout, int M, int N, int K){
  const int tid = threadIdx.x, wid = tid >> 6, lane = tid & 63;
  const int l15 = lane & 15, l4 = lane >> 4;
  const int bm = blockIdx.y * 128, bn = blockIdx.x * 128;
  const int wr = wid >> 1, wc = wid & 1;
  __shared__ __align__(16) unsigned short As[128 * 32];
  __shared__ __align__(16) unsigned short Bs[128 * 32];

  const int srow = wid * 32 + (lane >> 2);
  const int scol = (lane & 3) * 8;
  const unsigned short* pa0 = A  + (size_t)(bm + srow) * K + scol;
  const unsigned short* pa1 = pa0 + (size_t)16 * K;
  const unsigned short* pb0 = Bt + (size_t)(bn + srow) * K + scol;
  const unsigned short* pb1 = pb0 + (size_t)16 * K;
  unsigned short* la0 = As + wid * 1024;
  unsigned short* la1 = la0 + 512;
  unsigned short* lb0 = Bs + wid * 1024;
  unsigned short* lb1 = lb0 + 512;

  f32x4 acc[4][4];
  #pragma unroll
  for (int m2 = 0; m2 < 4; m2++)
    #pragma unroll
    for (int n2 = 0; n2 < 4; n2++) acc[m2][n2] = (f32x4){0.f, 0.f, 0.f, 0.f};

  for (int k0 = 0; k0 < K; k0 += 32){
    __syncthreads();
    gld16(la0, pa0 + k0);
    gld16(la1, pa1 + k0);
    gld16(lb0, pb0 + k0);
    gld16(lb1, pb1 + k0);
    __syncthreads();
    bf16x8 af[4], bfr[4];
    #pragma unroll
    for (int m2 = 0; m2 < 4; m2++) af[m2] = *(const bf16x8*)&As[(wr * 64 + m2 * 16 + l15) * 32 + l4 * 8];
    #pragma unroll
    for (int n2 = 0; n2 < 4; n2++) bfr[n2] = *(const bf16x8*)&Bs[(wc * 64 + n2 * 16 + l15) * 32 + l4 * 8];
    #pragma unroll
    for (int m2 = 0; m2 < 4; m2++)
      #pragma unroll
      for (int n2 = 0; n2 < 4; n2++)
        acc[m2][n2] = __builtin_amdgcn_mfma_f32_16x16x32_bf16(af[m2], bfr[n2], acc[m2][n2], 0, 0, 0);
  }
  #pragma unroll
  for (int m2 = 0; m2 < 4; m2++)
    #pragma unroll
    for (int n2 = 0; n2 < 4; n2++){
      int col = bn + wc * 64 + n2 * 16 + l15;
      float bias;
      if (MODE == 1) bias = col < 2048 ? b0[col] : (col < 2560 ? b1[col - 2048] : b2[col - 2560]);
      else           bias = b0[col];
      #pragma unroll
      for (int r = 0; r < 4; r++){
        int row = bm + wr * 64 + m2 * 16 + l4 * 4 + r;
        float v = acc[m2][n2][r] + bias;
        if (MODE == 1) ((unsigned short*)Cout)[(size_t)row * N + col] = f2bf(v);
        else           ((float*)Cout)[(size_t)row * N + col] = v;
      }
    }
}

// ---------------- fused RMSNorm + RoPE, in place on q/k parts of qkv ----------------
__global__ void rmsrope(unsigned short* __restrict__ qkv, const float* __restrict__ qn,
                        const float* __restrict__ kn){
  const int w = blockIdx.x * 4 + (threadIdx.x >> 6);
  const int lane = threadIdx.x & 63;
  const int t = w / 20, sub = w % 20;
  const int s = t & (S_ - 1);
  const bool isq = sub < 16;
  unsigned short* row;
  const float* sc;
  if (isq){ row = qkv + (size_t)t * NQKV_ + sub * HD_; sc = qn; }
  else    { row = qkv + (size_t)t * NQKV_ + 2048 + (sub - 16) * HD_; sc = kn; }
  unsigned int pr = *(const unsigned int*)&row[2 * lane];
  float xe = bf2f((unsigned short)(pr & 0xffffu));
  float xo = bf2f((unsigned short)(pr >> 16));
  float ss = xe * xe + xo * xo;
  #pragma unroll
  for (int o = 1; o < 64; o <<= 1) ss += __shfl_xor(ss, o);
  float rn = rsqrtf(ss * (1.0f / 128.0f) + EPS_);
  xe = xe * rn * sc[2 * lane];
  xo = xo * rn * sc[2 * lane + 1];
  float inv = exp2f((float)lane * -0.20762051f);
  float th = (float)s * inv;
  float sn = __sinf(th), cs = __cosf(th);
  float oe = xe * cs - xo * sn;
  float oo = xe * sn + xo * cs;
  if (isq){ oe *= SCALE_; oo *= SCALE_; }
  *(unsigned int*)&row[2 * lane] = (unsigned int)f2bf(oe) | ((unsigned int)f2bf(oo) << 16);
}

// ---------------- V -> V^T per (b,g): vt[(bg*128+d)*1024 + s] ----------------
__global__ void vtrans(const unsigned short* __restrict__ qkv, unsigned short* __restrict__ vt){
  __shared__ unsigned short tile[64][65];
  const int s0 = blockIdx.x * 64, d0 = blockIdx.y * 64;
  const int bg = blockIdx.z, b = bg >> 2, g = bg & 3;
  const int c = threadIdx.x & 63, rb = threadIdx.x >> 6;
  #pragma unroll
  for (int j = 0; j < 16; j++){
    int r = rb + j * 4;
    tile[r][c] = qkv[((size_t)b * S_ + s0 + r) * NQKV_ + 2560 + g * HD_ + d0 + c];
  }
  __syncthreads();
  #pragma unroll
  for (int j = 0; j < 16; j++){
    int r = rb + j * 4;
    vt[((size_t)bg * HD_ + d0 + r) * (size_t)S_ + s0 + c] = tile[c][r];
  }
}

// ---------------- flash attention: 32x32 MFMA, swapped QK^T, in-reg softmax ----
// Block = 4 waves = 4 heads of group g, 32 q-rows. Lane owns q-col (l&31);
// S^T[key][q] via mfma(A=K, B=Q); keys live in regs (crow(r,hi)); softmax is
// lane-local + one shfl_xor(32). P packed to bf16 in-reg (8 shfl). K,V dbuf LDS.
__global__ __launch_bounds__(256, 2) void attn(const unsigned short* __restrict__ qkv,
    const unsigned short* __restrict__ vt, unsigned short* __restrict__ outb){
  const int bid = blockIdx.x;
  const int xcd = bid & 7, idx = bid >> 3;
  const int gb = xcd * 2 + (idx & 1);
  const int qh = idx >> 1;
  const int qt = (qh < 16) ? (31 - qh) : (qh - 16);   // CU pair (qt, 31-qt): even work
  const int g = gb & 3, b = gb >> 2;
  const int tid = threadIdx.x, w = tid >> 6, lane = tid & 63;
  const int h = g * 4 + w;
  const int l31 = lane & 31, hi = lane >> 5;
  const int nkt = qt / 2 + 1;
  __shared__ __align__(16) unsigned short Ks[2][64 * 128];  // swz: col ^= (row&15)<<3
  __shared__ __align__(16) unsigned short Vs[2][128 * 64];  // swz: col ^= (row&7)<<3

  #define STAGE_KV(BF, KT)                                                              \
    do {                                                                                \
      _Pragma("unroll")                                                                 \
      for (int i_ = 0; i_ < 4; i_++){                                                   \
        int row_ = w * 16 + i_ * 4 + (lane >> 4);                                       \
        const unsigned short* src_ = qkv + (size_t)(b * S_ + (KT) * 64 + row_) * NQKV_  \
            + 2048 + g * HD_ + (((lane & 15) * 8) ^ ((row_ & 15) << 3));                \
        gld16(&Ks[BF][(w * 16 + i_ * 4) * 128], src_);                                  \
      }                                                                                 \
      _Pragma("unroll")                                                                 \
      for (int i_ = 0; i_ < 4; i_++){                                                   \
        int row_ = w * 32 + i_ * 8 + (lane >> 3);                                       \
        const unsigned short* src_ = vt + (size_t)((b * G_ + g) * HD_ + row_) * S_      \
            + (KT) * 64 + (((lane & 7) * 8) ^ ((row_ & 7) << 3));                       \
        gld16(&Vs[BF][(w * 32 + i_ * 8) * 64], src_);                                   \
      }                                                                                 \
    } while (0)

  // Q fragments (B operand): lane -> Q[q = l31][d = ks*16 + hi*8 + j]
  bf16x8 qf[8];
  {
    const unsigned short* qp = qkv + ((size_t)b * S_ + qt * 32 + l31) * NQKV_ + h * HD_ + hi * 8;
    #pragma unroll
    for (int ks = 0; ks < 8; ks++) qf[ks] = *(const bf16x8*)&qp[ks * 16];
  }
  f32x16 o[4];
  #pragma unroll
  for (int d2 = 0; d2 < 4; d2++)
    #pragma unroll
    for (int r = 0; r < 16; r++) o[d2][r] = 0.f;
  float m_ = -1e30f, l_ = 0.f;

  int bf = 0;
  STAGE_KV(0, 0);
  __syncthreads();

  for (int kt = 0; kt < nkt; ++kt){
    if (kt + 1 < nkt){
      if (bf) STAGE_KV(0, kt + 1); else STAGE_KV(1, kt + 1);
    }
    const unsigned short* KB = Ks[bf];
    const unsigned short* VB = Vs[bf];
    const bool diag = (kt == nkt - 1);

    // ---- S^T = K @ Q^T : sacc[kb][r] = S[key = kb*32+crow(r,hi)][q = l31] ----
    f32x16 sacc[2];
    #pragma unroll
    for (int kb = 0; kb < 2; kb++){
      f32x16 acc;
      #pragma unroll
      for (int r = 0; r < 16; r++) acc[r] = 0.f;
      __builtin_amdgcn_s_setprio(1);
      #pragma unroll
      for (int ks = 0; ks < 8; ks++){
        bf16x8 kf = *(const bf16x8*)&KB[(kb * 32 + l31) * 128 + ((ks * 16 + hi * 8) ^ ((l31 & 15) << 3))];
        acc = __builtin_amdgcn_mfma_f32_32x32x16_bf16(kf, qf[ks], acc, 0, 0, 0);
      }
      __builtin_amdgcn_s_setprio(0);
      sacc[kb] = acc;
    }

    // ---- mask + scale ----
    if (diag){
      const int qrow = qt * 32 + l31;
      #pragma unroll
      for (int kb = 0; kb < 2; kb++)
        #pragma unroll
        for (int r = 0; r < 16; r++){
          int key = kt * 64 + kb * 32 + (r & 3) + 8 * (r >> 2) + 4 * hi;
          float v = sacc[kb][r] * SCALE_;
          sacc[kb][r] = (key > qrow) ? -1e30f : v;
        }
    } else {
      #pragma unroll
      for (int kb = 0; kb < 2; kb++)
        #pragma unroll
        for (int r = 0; r < 16; r++) sacc[kb][r] *= SCALE_;
    }

    // ---- row max (lane-local + 1 swap) ----
    float tm = sacc[0][0];
    #pragma unroll
    for (int r = 1; r < 16; r++) tm = fmaxf(tm, sacc[0][r]);
    #pragma unroll
    for (int r = 0; r < 16; r++) tm = fmaxf(tm, sacc[1][r]);
    tm = fmaxf(tm, __shfl_xor(tm, 32));

    // ---- defer-max (T13, THR=8): skip O-rescale when growth small ----
    float al = 1.0f;
    bool rescale = false;
    if (!__all(tm <= m_ + 8.0f)){
      float mn = fmaxf(m_, tm);
      al = __expf(m_ - mn);
      m_ = mn;
      rescale = true;
    }

    // ---- exp + row sum ----
    float rs = 0.f;
    #pragma unroll
    for (int kb = 0; kb < 2; kb++)
      #pragma unroll
      for (int r = 0; r < 16; r++){
        float p = __expf(sacc[kb][r] - m_);
        sacc[kb][r] = p;
        rs += p;
      }
    rs += __shfl_xor(rs, 32);
    l_ = l_ * al + rs;

    if (rescale){
      #pragma unroll
      for (int r = 0; r < 16; r++){
        float alr = __shfl(al, (r & 3) + 8 * (r >> 2) + 4 * hi);
        #pragma unroll
        for (int d2 = 0; d2 < 4; d2++) o[d2][r] *= alr;
      }
    }

    // ---- pack P to bf16 words; build PA fragments via 8 shfl_xor(32) ----
    unsigned int u[2][4][2];
    #pragma unroll
    for (int kb = 0; kb < 2; kb++)
      #pragma unroll
      for (int t = 0; t < 4; t++)
        #pragma unroll
        for (int wd = 0; wd < 2; wd++)
          u[kb][t][wd] = (unsigned int)f2bf(sacc[kb][4 * t + 2 * wd])
                       | ((unsigned int)f2bf(sacc[kb][4 * t + 2 * wd + 1]) << 16);

    bf16x8 pa[4];
    #pragma unroll
    for (int ks = 0; ks < 4; ks++){
      const int kb = ks >> 1, s2 = ks & 1;
      unsigned int v0 = hi ? u[kb][2 * s2][0] : u[kb][2 * s2 + 1][0];
      unsigned int v1 = hi ? u[kb][2 * s2][1] : u[kb][2 * s2 + 1][1];
      unsigned int x0 = (unsigned int)__shfl_xor((int)v0, 32);
      unsigned int x1 = (unsigned int)__shfl_xor((int)v1, 32);
      union { bf16x8 v; unsigned int w[4]; } pw;
      pw.w[0] = hi ? x0 : u[kb][2 * s2][0];
      pw.w[1] = hi ? x1 : u[kb][2 * s2][1];
      pw.w[2] = hi ? u[kb][2 * s2 + 1][0] : x0;
      pw.w[3] = hi ? u[kb][2 * s2 + 1][1] : x1;
      pa[ks] = pw.v;
    }

    // ---- PV: O[q=crow(r,hi)][d=d2*32+l31] += P @ V ----
    __builtin_amdgcn_s_setprio(1);
    #pragma unroll
    for (int d2 = 0; d2 < 4; d2++){
      #pragma unroll
      for (int ks = 0; ks < 4; ks++){
        bf16x8 vf = *(const bf16x8*)&VB[(d2 * 32 + l31) * 64 + ((ks * 16 + hi * 8) ^ ((l31 & 7) << 3))];
        o[d2] = __builtin_amdgcn_mfma_f32_32x32x16_bf16(pa[ks], vf, o[d2], 0, 0, 0);
      }
    }
    __builtin_amdgcn_s_setprio(0);
    __syncthreads();
    bf ^= 1;
  }

  // ---- epilogue: divide by l (per-reg row) and store ----
  float lrcp[16];
  #pragma unroll
  for (int r = 0; r < 16; r++)
    lrcp[r] = 1.0f / __shfl(l_, (r & 3) + 8 * (r >> 2) + 4 * hi);
  #pragma unroll
  for (int d2 = 0; d2 < 4; d2++)
    #pragma unroll
    for (int r = 0; r < 16; r++){
      size_t row = (size_t)b * S_ + qt * 32 + (r & 3) + 8 * (r >> 2) + 4 * hi;
      outb[row * D_ + h * HD_ + d2 * 32 + l31] = f2bf(o[d2][r] * lrcp[r]);
    }
  #undef STAGE_KV
}

extern "C" void kernel_launch(void* const* d_in, const int* in_sizes, int n_in,
                              void* d_out, int out_size, void* d_ws, size_t ws_size,
                              hipStream_t stream){
  const float* x  = (const float*)d_in[0];
  const float* Wq = (const float*)d_in[1];
  const float* bq = (const float*)d_in[2];
  const float* Wk = (const float*)d_in[3];
  const float* bk = (const float*)d_in[4];
  const float* Wv = (const float*)d_in[5];
  const float* bv = (const float*)d_in[6];
  const float* Wo = (const float*)d_in[7];
  const float* bo = (const float*)d_in[8];
  const float* qn = (const float*)d_in[9];
  const float* kn = (const float*)d_in[10];
  float* out = (float*)d_out;

  char* ws = (char*)d_ws;
  unsigned short* xb    = (unsigned short*)(ws + 0);          // 16,777,216 B
  unsigned short* wqkvT = (unsigned short*)(ws + 16777216);   // 12,582,912 B
  unsigned short* woT   = (unsigned short*)(ws + 29360128);   //  8,388,608 B
  unsigned short* qkv   = (unsigned short*)(ws + 37748736);   // 25,165,824 B
  unsigned short* attnO = (unsigned short*)(ws + 62914560);   // 16,777,216 B
  unsigned short* vt    = (unsigned short*)(ws + 79691776);   //  4,194,304 B

  cvt_bf16<<<8192, 256, 0, stream>>>(x, xb);
  transpose_cvt<<<dim3(32, 32), 256, 0, stream>>>(Wq, wqkvT, 2048, 0);
  transpose_cvt<<<dim3(8, 32),  256, 0, stream>>>(Wk, wqkvT, 512, 2048);
  transpose_cvt<<<dim3(8, 32),  256, 0, stream>>>(Wv, wqkvT, 512, 2560);
  transpose_cvt<<<dim3(32, 32), 256, 0, stream>>>(Wo, woT, 2048, 0);
  gemm_bt<1><<<dim3(24, 32), 256, 0, stream>>>(xb, wqkvT, bq, bk, bv, (void*)qkv, 4096, 3072, 2048);
  rmsrope<<<20480, 256, 0, stream>>>(qkv, qn, kn);
  vtrans<<<dim3(16, 2, 16), 256, 0, stream>>>(qkv, vt);
  attn<<<512, 256, 0, stream>>>(qkv, vt, attnO);
  gemm_bt<0><<<dim3(16, 32), 256, 0, stream>>>(attnO, woT, bo, nullptr, nullptr, (void*)out, 4096, 2048, 2048);
}